// Round 8
// baseline (1459.075 us; speedup 1.0000x reference)
//
#include <hip/hip_runtime.h>
#include <stdint.h>

#define N 8192
#define D 512
#define NEG -1e30f

typedef _Float16 f16;
typedef f16 f16x4 __attribute__((ext_vector_type(4)));
typedef f16 f16x8 __attribute__((ext_vector_type(8)));
typedef float f32x4v __attribute__((ext_vector_type(4)));
typedef float f32x16 __attribute__((ext_vector_type(16)));

// ---- workspace layout (bytes) ----
// XH (8M, dead after qkv) is overlaid by partial P0.
#define XH_OFF   0ull
#define WQH_OFF  (XH_OFF + 8192ull * 512 * 2)
#define WKH_OFF  (WQH_OFF + 512ull * 512 * 2)
#define WVH_OFF  (WKH_OFF + 512ull * 512 * 2)
#define QH_OFF   (WVH_OFF + 512ull * 512 * 2)
#define KH_OFF   (QH_OFF + 8192ull * 512 * 2)
#define VT_OFF   (KH_OFF + 8192ull * 512 * 2)
#define PART_SZ  (8192ull * 512 * 2)                // one fp16 partial, 8 MB
#define P123_OFF (VT_OFF + 8192ull * 512 * 2)

// attn LDS: Qs 32 rows x 1040 B + 4 wave P slabs; merge reuses Q area.
#define QROW   1040
#define QS_SZ  (32 * QROW)          // 33280
#define PSLAB  1280                 // 16 rows x 80 B
#define LDSB   (QS_SZ + 4 * PSLAB)  // 38400 -> 3+ blocks/CU (VGPR-capped at 3)

// ---------------- fp32 -> fp16 conversion (X and the three W's) ----------------
__global__ __launch_bounds__(256) void cvt_fp16(
    const float* __restrict__ X,
    const float* __restrict__ Wq, const float* __restrict__ Wk, const float* __restrict__ Wv,
    f16* __restrict__ Xh,
    f16* __restrict__ Wqh, f16* __restrict__ Wkh, f16* __restrict__ Wvh)
{
    const int idx = blockIdx.x * 256 + threadIdx.x;
    const float* src; f16* dst; int off;
    if (idx < 1048576)      { src = X;  dst = Xh;  off = idx; }
    else if (idx < 1114112) { src = Wq; dst = Wqh; off = idx - 1048576; }
    else if (idx < 1179648) { src = Wk; dst = Wkh; off = idx - 1114112; }
    else                    { src = Wv; dst = Wvh; off = idx - 1179648; }
    const float4 v = ((const float4*)src)[off];
    f16x4 h; h.x = (f16)v.x; h.y = (f16)v.y; h.z = (f16)v.z; h.w = (f16)v.w;
    *(f16x4*)(dst + (size_t)off * 4) = h;
}

// ---------------- QKV via MFMA (unchanged) ----------------
__global__ __launch_bounds__(256) void qkv_mfma(
    const f16* __restrict__ Xh,
    const f16* __restrict__ Wqh, const f16* __restrict__ Wkh, const f16* __restrict__ Wvh,
    f16* __restrict__ qh, f16* __restrict__ kh, f16* __restrict__ vt)
{
    const int t    = threadIdx.x;
    const int w    = t >> 6;
    const int lane = t & 63;
    const int lo   = lane & 31;
    const int hi   = lane >> 5;
    const int z    = blockIdx.z;

    int m0, c0; const f16 *Ap, *Bp; f16* Yp; size_t ldy;
    if (z == 2) {
        m0 = blockIdx.x * 128 + w * 32; c0 = blockIdx.y * 128;
        Ap = Wvh; Bp = Xh; Yp = vt; ldy = N;
    } else {
        m0 = blockIdx.y * 128 + w * 32; c0 = blockIdx.x * 128;
        Ap = Xh; Bp = z ? Wkh : Wqh; Yp = z ? kh : qh; ldy = D;
    }

    const f16* arow = Ap + (size_t)(m0 + lo) * D + hi * 8;
    const f16* brow[4];
#pragma unroll
    for (int nn = 0; nn < 4; ++nn)
        brow[nn] = Bp + (size_t)(c0 + nn * 32 + lo) * D + hi * 8;

    f32x16 acc[4];
#pragma unroll
    for (int nn = 0; nn < 4; ++nn)
#pragma unroll
        for (int e = 0; e < 16; ++e) acc[nn][e] = 0.f;

#pragma unroll 4
    for (int ks = 0; ks < 32; ++ks) {
        const f16x8 a = *(const f16x8*)(arow + ks * 16);
#pragma unroll
        for (int nn = 0; nn < 4; ++nn) {
            const f16x8 b = *(const f16x8*)(brow[nn] + ks * 16);
            acc[nn] = __builtin_amdgcn_mfma_f32_32x32x16_f16(a, b, acc[nn], 0, 0, 0);
        }
    }

#pragma unroll
    for (int nn = 0; nn < 4; ++nn)
#pragma unroll
        for (int r = 0; r < 16; ++r) {
            const int row = m0 + (r & 3) + 8 * (r >> 2) + 4 * hi;
            Yp[(size_t)row * ldy + c0 + nn * 32 + lo] = (f16)acc[nn][r];
        }
}

// ---------------- attention v3: occupancy-fixed flash ----------------
// grid = 256 j-tiles (32 rows) x nib i-blocks (nib = gridDim.x/256: 4 or 2).
// 256 thr = 4 waves: jw = w&1 (16-row j-subgroup), iw = w>>1 (i-interleave).
// Inner loop identical to v2 (swapped-QK^T, in-register softmax, wave-private
// P slab). After the loop: 2-way iw-merge in LDS, fp16 unnormalized partial +
// (m,l) per i-block; merge_p combines i-blocks.
__global__ __launch_bounds__(256, 3) void attn_v3(
    const f16* __restrict__ qh, const f16* __restrict__ kh,
    const f16* __restrict__ vt, const int* __restrict__ adj,
    f16* __restrict__ part0, f16* __restrict__ part123, float2* __restrict__ ml)
{
    extern __shared__ char smem[];
    char* Qs = smem;
    char* Pw = smem + QS_SZ + (threadIdx.x >> 6) * PSLAB;

    const int t    = threadIdx.x;
    const int lane = t & 63;
    const int jl   = lane & 15;
    const int g    = lane >> 4;
    const int w    = t >> 6;
    const int jw   = w & 1;
    const int iw   = w >> 1;

    // XCD swizzle: i-block pinned to an XCD group; bijective jt mapping.
    const int nib = gridDim.x >> 8;         // 4 or 2
    const int b   = blockIdx.x;
    const int xcd = b & 7;
    const int u   = b >> 3;
    int ib, jt;
    if (nib == 4) { ib = xcd >> 1; jt = (xcd & 1) * 128 + u; }
    else          { ib = xcd >> 2; jt = (xcd & 3) * 64  + u; }
    const int j0      = jt * 32;
    const int irange  = N / nib;
    const int ibase   = ib * irange;
    const int iters   = irange >> 6;        // 32 (nib=4) or 64 (nib=2)
    const int iw_base = ibase + iw * 32;

    f16* pb = (ib == 0) ? part0 : part123 + (size_t)(ib - 1) * ((size_t)N * D);

    // ---- stage Q[j0..j0+31][*] into Qs ----
    for (int c = t; c < 32 * 64; c += 256) {
        const int row = c >> 6, off = c & 63;
        f16x8 v = *(const f16x8*)(qh + (size_t)(j0 + row) * D + off * 8);
        *(f16x8*)(Qs + row * QROW + off * 16) = v;
    }
    __syncthreads();

    f32x4v oacc[32];
#pragma unroll
    for (int c = 0; c < 32; ++c) { oacc[c][0]=0.f; oacc[c][1]=0.f; oacc[c][2]=0.f; oacc[c][3]=0.f; }
    float m_run = NEG, l_run = 0.f;

    const char* qrd   = Qs + (jw * 16 + jl) * QROW + g * 16;
    const f16*  kbase = kh + (size_t)(iw_base + jl) * D + g * 8;
    const f16*  vbase = vt + (size_t)jl * N + iw_base + g * 8;
    const int*  abase = adj + (size_t)(iw_base + g * 4) * N + j0 + jw * 16 + jl;
    char* pwr0 = Pw + jl * 80 + g * 8;
    const char* prd = Pw + jl * 80 + g * 16;

    for (int it = 0; it < iters; ++it) {
        const f16* kt = kbase + (size_t)it * 64 * D;
        const int* at = abase + (size_t)it * 64 * N;

        // ---- adjacency masks ----
        int msk[2][4];
#pragma unroll
        for (int a = 0; a < 2; ++a)
#pragma unroll
            for (int rg = 0; rg < 4; ++rg)
                msk[a][rg] = at[(size_t)(a * 16 + rg) * N];

        // ---- QK^T ----
        f32x4v sa0, sa1;
        sa0[0]=0.f;sa0[1]=0.f;sa0[2]=0.f;sa0[3]=0.f;
        sa1[0]=0.f;sa1[1]=0.f;sa1[2]=0.f;sa1[3]=0.f;
#pragma unroll 4
        for (int ks = 0; ks < 16; ++ks) {
            f16x8 qf = *(const f16x8*)(qrd + ks * 64);
            f16x8 k0 = *(const f16x8*)(kt + ks * 32);
            f16x8 k1 = *(const f16x8*)(kt + (size_t)16 * D + ks * 32);
            sa0 = __builtin_amdgcn_mfma_f32_16x16x32_f16(k0, qf, sa0, 0, 0, 0);
            sa1 = __builtin_amdgcn_mfma_f32_16x16x32_f16(k1, qf, sa1, 0, 0, 0);
        }

        // ---- masked in-register online softmax (per j = jl) ----
        float s[2][4];
        float mt = NEG;
#pragma unroll
        for (int rg = 0; rg < 4; ++rg) {
            s[0][rg] = msk[0][rg] ? sa0[rg] : NEG;
            s[1][rg] = msk[1][rg] ? sa1[rg] : NEG;
            mt = fmaxf(mt, fmaxf(s[0][rg], s[1][rg]));
        }
        mt = fmaxf(mt, __shfl_xor(mt, 16, 64));
        mt = fmaxf(mt, __shfl_xor(mt, 32, 64));

        if (__any(mt > m_run)) {            // defer-rescale
            const float m_new = fmaxf(m_run, mt);
            const float sc = __expf(m_run - m_new);
            m_run = m_new;
            l_run *= sc;
            float scr[4];
#pragma unroll
            for (int rg = 0; rg < 4; ++rg) scr[rg] = __shfl(sc, g * 4 + rg, 64);
#pragma unroll
            for (int c = 0; c < 32; ++c) {
                oacc[c][0] *= scr[0]; oacc[c][1] *= scr[1];
                oacc[c][2] *= scr[2]; oacc[c][3] *= scr[3];
            }
        }

        float p[2][4];
        float ps = 0.f;
#pragma unroll
        for (int a = 0; a < 2; ++a)
#pragma unroll
            for (int rg = 0; rg < 4; ++rg) {
                const float pe = msk[a][rg] ? __expf(s[a][rg] - m_run) : 0.f;
                p[a][rg] = pe;
                ps += pe;
            }
        ps += __shfl_xor(ps, 16, 64);
        ps += __shfl_xor(ps, 32, 64);
        l_run += ps;

        // ---- pack P (f16) -> wave-private slab ----
        {
            union { f16 h[8]; uint2 u2[2]; } pc;
#pragma unroll
            for (int a = 0; a < 2; ++a)
#pragma unroll
                for (int rg = 0; rg < 4; ++rg)
                    pc.h[a * 4 + rg] = (f16)p[a][rg];
            *(uint2*)(pwr0)      = pc.u2[0];
            *(uint2*)(pwr0 + 32) = pc.u2[1];
        }

        // ---- PV ----
        const f16x8 pa = *(const f16x8*)(prd);
        const f16* vtile = vbase + it * 64;
#pragma unroll
        for (int c = 0; c < 32; ++c) {
            f16x8 vf = *(const f16x8*)(vtile + (size_t)c * 16 * N);
            oacc[c] = __builtin_amdgcn_mfma_f32_16x16x32_f16(pa, vf, oacc[c], 0, 0, 0);
        }
    }

    // ================= in-block 2-way iw merge =================
    float* mlx = (float*)(smem + QS_SZ);     // [4 waves][16 jl][2], slabs dead
    float* Oex = (float*)smem;               // 2 jw x 16 rows x 256 cols fp32 = 32 KB

    __syncthreads();                          // all PV + Q reads complete
    if (g == 0) {
        mlx[(w * 16 + jl) * 2 + 0] = m_run;
        mlx[(w * 16 + jl) * 2 + 1] = l_run;
    }
    __syncthreads();

    const int pw = (iw ? w - 2 : w + 2);      // partner wave (same jw)
    const float m_p = mlx[(pw * 16 + jl) * 2 + 0];
    const float l_p = mlx[(pw * 16 + jl) * 2 + 1];
    const float m_g = fmaxf(m_run, m_p);
    const float e_s = __expf(m_run - m_g);    // exp(NEG-NEG)=1, harmless (oacc=0)
    const float l_g = e_s * l_run + __expf(m_p - m_g) * l_p;

    // pre-scale oacc rows by this wave's e (row j = g*4+rg -> factor from lane g*4+rg)
    {
        float er[4];
#pragma unroll
        for (int rg = 0; rg < 4; ++rg) er[rg] = __shfl(e_s, g * 4 + rg, 64);
#pragma unroll
        for (int c = 0; c < 32; ++c) {
            oacc[c][0] *= er[0]; oacc[c][1] *= er[1];
            oacc[c][2] *= er[2]; oacc[c][3] *= er[3];
        }
    }
    __syncthreads();                          // mlx reads done before Oex overwrites

#pragma unroll
    for (int ph = 0; ph < 2; ++ph) {
        if (iw == 1) {
#pragma unroll
            for (int c16 = 0; c16 < 16; ++c16)
#pragma unroll
                for (int rg = 0; rg < 4; ++rg)
                    Oex[jw * 4096 + (g * 4 + rg) * 256 + c16 * 16 + jl] = oacc[ph * 16 + c16][rg];
        }
        __syncthreads();
        if (iw == 0) {
#pragma unroll
            for (int c16 = 0; c16 < 16; ++c16)
#pragma unroll
                for (int rg = 0; rg < 4; ++rg) {
                    const float o = oacc[ph * 16 + c16][rg] +
                                    Oex[jw * 4096 + (g * 4 + rg) * 256 + c16 * 16 + jl];
                    pb[(size_t)(j0 + jw * 16 + g * 4 + rg) * D + (ph * 16 + c16) * 16 + jl] = (f16)o;
                }
        }
        __syncthreads();
    }

    if (iw == 0 && g == 0) {
        float2 v; v.x = m_g; v.y = l_g;
        ml[(size_t)ib * N + j0 + jw * 16 + jl] = v;
    }
}

// ---------------- merge the i-block partials ----------------
__global__ __launch_bounds__(256) void merge_p(
    float* __restrict__ out, const f16* __restrict__ p0,
    const f16* __restrict__ p123, const float2* __restrict__ ml, int nib)
{
    const int idx = blockIdx.x * 256 + threadIdx.x;   // one float4 of out
    const int j = idx >> 7;
    const int col = (idx & 127) * 4;

    float m_g = NEG;
    for (int ib = 0; ib < nib; ++ib) m_g = fmaxf(m_g, ml[(size_t)ib * N + j].x);
    float L = 0.f;
    float4 acc; acc.x = 0.f; acc.y = 0.f; acc.z = 0.f; acc.w = 0.f;
    for (int ib = 0; ib < nib; ++ib) {
        const float2 a = ml[(size_t)ib * N + j];
        const float e = __expf(a.x - m_g);
        L += e * a.y;
        const f16* pp = (ib == 0) ? p0 : p123 + (size_t)(ib - 1) * ((size_t)N * D);
        const f16x4 h = *(const f16x4*)(pp + (size_t)j * D + col);
        acc.x += e * (float)h.x; acc.y += e * (float)h.y;
        acc.z += e * (float)h.z; acc.w += e * (float)h.w;
    }
    const float inv = (L > 0.f) ? 1.f / L : 0.f;
    float4 r; r.x = acc.x * inv; r.y = acc.y * inv; r.z = acc.z * inv; r.w = acc.w * inv;
    ((float4*)out)[idx] = r;
}

extern "C" void kernel_launch(void* const* d_in, const int* in_sizes, int n_in,
                              void* d_out, int out_size, void* d_ws, size_t ws_size,
                              hipStream_t stream) {
    const float* ns  = (const float*)d_in[0];
    const int*   adj = (const int*)d_in[1];
    const float* Wq  = (const float*)d_in[2];
    const float* Wk  = (const float*)d_in[3];
    const float* Wv  = (const float*)d_in[4];

    char* ws = (char*)d_ws;
    f16*   Xh   = (f16*)(ws + XH_OFF);
    f16*   Wqh  = (f16*)(ws + WQH_OFF);
    f16*   Wkh  = (f16*)(ws + WKH_OFF);
    f16*   Wvh  = (f16*)(ws + WVH_OFF);
    f16*   qh   = (f16*)(ws + QH_OFF);
    f16*   kh   = (f16*)(ws + KH_OFF);
    f16*   vt   = (f16*)(ws + VT_OFF);
    f16*   p0   = (f16*)(ws + XH_OFF);          // overlays dead XH
    f16*   p123 = (f16*)(ws + P123_OFF);
    float* out  = (float*)d_out;

    // choose i-block count by available workspace
    const size_t need4 = P123_OFF + 3 * PART_SZ + 4ull * N * sizeof(float2);
    int nib; size_t ml_off;
    if (ws_size >= need4) { nib = 4; ml_off = P123_OFF + 3 * PART_SZ; }
    else                  { nib = 2; ml_off = P123_OFF + 1 * PART_SZ; }
    float2* mlb = (float2*)(ws + ml_off);

    cvt_fp16<<<4864, 256, 0, stream>>>(ns, Wq, Wk, Wv, Xh, Wqh, Wkh, Wvh);
    qkv_mfma<<<dim3(4, 64, 3), 256, 0, stream>>>(Xh, Wqh, Wkh, Wvh, qh, kh, vt);
    attn_v3<<<256 * nib, 256, LDSB, stream>>>(qh, kh, vt, adj, p0, p123, mlb);
    merge_p<<<4096, 256, 0, stream>>>(out, p0, p123, mlb, nib);
}